// Round 1
// baseline (2188.446 us; speedup 1.0000x reference)
//
#include <hip/hip_runtime.h>

#define BATCH 2
#define SEQ   1024
#define DM    768
#define NH    12
#define DK    64

// ---------------- ws layout (float offsets) ----------------
#define OFF_QS    0
#define OFF_KS    1572864
#define OFF_VS    3145728
#define OFF_ATTN  4718592
#define OFF_SC    6291456

// ============ GEMM: C = alpha*(X[2048,768] @ W[768,768] + b) ============
// grid (32,12), 256 thr. Wave owns 16 X-rows (scalar-loaded); lane = output col.
// W columns read lane-coalesced from global (L2/L3-resident). No LDS, no barriers.
__global__ __launch_bounds__(256) void gemm_bias_kernel(
    const float* __restrict__ X, const float* __restrict__ W,
    const float* __restrict__ bias, float* __restrict__ C, float alpha)
{
    const int bm = blockIdx.x, bn = blockIdx.y;
    const int tid = threadIdx.x;
    const int lane = tid & 63;
    const int wid = __builtin_amdgcn_readfirstlane(tid >> 6);
    const int col = bn * 64 + lane;
    const float* xrow = X + (size_t)(bm * 64 + wid * 16) * DM;
    const float* wcol = W + col;
    float acc[16] = {};
    for (int k4 = 0; k4 < DM; k4 += 4) {
        float w0 = wcol[(size_t)(k4 + 0) * DM];
        float w1 = wcol[(size_t)(k4 + 1) * DM];
        float w2 = wcol[(size_t)(k4 + 2) * DM];
        float w3 = wcol[(size_t)(k4 + 3) * DM];
#pragma unroll
        for (int r = 0; r < 16; ++r) {
            float4 x4 = *(const float4*)&xrow[(size_t)r * DM + k4];
            acc[r] = fmaf(x4.x, w0, acc[r]);
            acc[r] = fmaf(x4.y, w1, acc[r]);
            acc[r] = fmaf(x4.z, w2, acc[r]);
            acc[r] = fmaf(x4.w, w3, acc[r]);
        }
    }
    const float bcol = bias[col];
    float* crow = C + (size_t)(bm * 64 + wid * 16) * DM + col;
#pragma unroll
    for (int r = 0; r < 16; ++r) crow[(size_t)r * DM] = alpha * (acc[r] + bcol);
}

// ============ qk logits: scores[b,h,q,k] = qs[b,q,h,:] . ks[b,k,h,:] ============
// grid (kt=16, qt=16, bh=24). K-tile transposed into LDS once, then each lane
// holds its K column in 64 VGPRs; q rows are wave-uniform scalar loads.
__global__ __launch_bounds__(256) void qk_kernel(
    const float* __restrict__ qs, const float* __restrict__ ks,
    float* __restrict__ scores)
{
    const int kt = blockIdx.x, qt = blockIdx.y, bh = blockIdx.z;
    const int b = bh / NH, h = bh % NH;
    __shared__ float Kt[64][65];   // [d][k]
    const int tid = threadIdx.x;
    const int lane = tid & 63;
    const int wid = __builtin_amdgcn_readfirstlane(tid >> 6);
#pragma unroll
    for (int l = 0; l < 4; ++l) {
        int idx = tid + l * 256;
        int m = idx >> 4, d4 = idx & 15;
        float4 t = *(const float4*)&ks[(size_t)(b * SEQ + kt * 64 + m) * DM + h * 64 + d4 * 4];
        Kt[d4 * 4 + 0][m] = t.x;
        Kt[d4 * 4 + 1][m] = t.y;
        Kt[d4 * 4 + 2][m] = t.z;
        Kt[d4 * 4 + 3][m] = t.w;
    }
    __syncthreads();
    float kreg[64];
#pragma unroll
    for (int d = 0; d < 64; ++d) kreg[d] = Kt[d][lane];

    const float* qbase = qs + (size_t)(b * SEQ + qt * 64 + wid * 16) * DM + h * 64;
    float* srow = scores + ((size_t)bh * SEQ + qt * 64 + wid * 16) * SEQ + kt * 64 + lane;
#pragma unroll 4
    for (int r = 0; r < 16; ++r) {
        const float* qr = qbase + (size_t)r * DM;
        float a0 = 0.f, a1 = 0.f, a2 = 0.f, a3 = 0.f;
#pragma unroll
        for (int dq = 0; dq < 16; ++dq) {
            float4 q4 = *(const float4*)&qr[dq * 4];
            a0 = fmaf(q4.x, kreg[dq * 4 + 0], a0);
            a1 = fmaf(q4.y, kreg[dq * 4 + 1], a1);
            a2 = fmaf(q4.z, kreg[dq * 4 + 2], a2);
            a3 = fmaf(q4.w, kreg[dq * 4 + 3], a3);
        }
        srow[(size_t)r * SEQ] = (a0 + a1) + (a2 + a3);
    }
}

// ============ rel-k logits: scores[b,h,q,k] += qs[b,q,h,:] . rk[b,q,k,:] ============
// grid (kc=4, q=1024, b=2). rk chunk LDS-staged (amortized over 12 heads);
// q read as wave-uniform scalar float4 loads (hot in scalar cache).
__global__ __launch_bounds__(256) void relk_kernel(
    const float* __restrict__ qs, const float* __restrict__ rk,
    float* __restrict__ scores)
{
    const int kc = blockIdx.x, q = blockIdx.y, b = blockIdx.z;
    __shared__ float Rs[64][65];
    const int tid = threadIdx.x;
    const int k = tid & 63;
    const int hb = __builtin_amdgcn_readfirstlane(tid >> 6);  // heads hb, hb+4, hb+8
    const float* qrow = qs + (size_t)(b * SEQ + q) * DM;
    const size_t rbase = ((size_t)(b * SEQ + q)) * SEQ * DK;
    for (int sub = 0; sub < 4; ++sub) {
        const int k0 = kc * 256 + sub * 64;
        __syncthreads();
#pragma unroll
        for (int l = 0; l < 4; ++l) {
            int idx = tid + l * 256;
            int kk = idx >> 4, d4 = idx & 15;
            float4 t = *(const float4*)&rk[rbase + (size_t)(k0 + kk) * DK + d4 * 4];
            Rs[kk][d4 * 4 + 0] = t.x;
            Rs[kk][d4 * 4 + 1] = t.y;
            Rs[kk][d4 * 4 + 2] = t.z;
            Rs[kk][d4 * 4 + 3] = t.w;
        }
        __syncthreads();
        float a0 = 0.f, a1 = 0.f, a2 = 0.f;
#pragma unroll
        for (int dq = 0; dq < 16; ++dq) {
            float4 q0 = *(const float4*)&qrow[(hb    ) * 64 + dq * 4];
            float4 q1 = *(const float4*)&qrow[(hb + 4) * 64 + dq * 4];
            float4 q2 = *(const float4*)&qrow[(hb + 8) * 64 + dq * 4];
            float r0 = Rs[k][dq * 4 + 0];
            float r1 = Rs[k][dq * 4 + 1];
            float r2 = Rs[k][dq * 4 + 2];
            float r3 = Rs[k][dq * 4 + 3];
            a0 = fmaf(r0, q0.x, fmaf(r1, q0.y, fmaf(r2, q0.z, fmaf(r3, q0.w, a0))));
            a1 = fmaf(r0, q1.x, fmaf(r1, q1.y, fmaf(r2, q1.z, fmaf(r3, q1.w, a1))));
            a2 = fmaf(r0, q2.x, fmaf(r1, q2.y, fmaf(r2, q2.z, fmaf(r3, q2.w, a2))));
        }
        size_t s0 = ((size_t)(b * NH + hb) * SEQ + q) * SEQ + k0 + k;
        scores[s0] += a0;
        scores[s0 + (size_t)4 * SEQ * SEQ] += a1;
        scores[s0 + (size_t)8 * SEQ * SEQ] += a2;
    }
}

// ============ softmax over last dim (1024), in place ============
__global__ __launch_bounds__(256) void softmax_kernel(float* __restrict__ scores)
{
    const int row = blockIdx.x;
    float* p = scores + (size_t)row * SEQ;
    const int tid = threadIdx.x;
    float4 x = *(float4*)&p[tid * 4];
    float m = fmaxf(fmaxf(x.x, x.y), fmaxf(x.z, x.w));
#pragma unroll
    for (int off = 32; off > 0; off >>= 1) m = fmaxf(m, __shfl_xor(m, off));
    __shared__ float redm[4], reds[4];
    if ((tid & 63) == 0) redm[tid >> 6] = m;
    __syncthreads();
    m = fmaxf(fmaxf(redm[0], redm[1]), fmaxf(redm[2], redm[3]));
    float e0 = __expf(x.x - m), e1 = __expf(x.y - m);
    float e2 = __expf(x.z - m), e3 = __expf(x.w - m);
    float s = e0 + e1 + e2 + e3;
#pragma unroll
    for (int off = 32; off > 0; off >>= 1) s += __shfl_xor(s, off);
    if ((tid & 63) == 0) reds[tid >> 6] = s;
    __syncthreads();
    float inv = 1.0f / (reds[0] + reds[1] + reds[2] + reds[3]);
    x.x = e0 * inv; x.y = e1 * inv; x.z = e2 * inv; x.w = e3 * inv;
    *(float4*)&p[tid * 4] = x;
}

// ============ wv: attn[b,q,h,:] = sum_k P[b,h,q,k] * vs[b,k,h,:] ============
// grid (qt=16, bh=24). Wave owns 16 q-rows (P via scalar loads); lane = d.
// V column streamed lane-coalesced from global (L1/L2-resident per block). No LDS.
__global__ __launch_bounds__(256) void wv_kernel(
    const float* __restrict__ scores, const float* __restrict__ vs,
    float* __restrict__ attn)
{
    const int qt = blockIdx.x, bh = blockIdx.y;
    const int b = bh / NH, h = bh % NH;
    const int tid = threadIdx.x;
    const int lane = tid & 63;
    const int wid = __builtin_amdgcn_readfirstlane(tid >> 6);
    const float* prow = scores + ((size_t)bh * SEQ + qt * 64 + wid * 16) * SEQ;
    const float* vcol = vs + (size_t)b * SEQ * DM + h * 64 + lane;
    float acc[16] = {};
    for (int k4 = 0; k4 < SEQ; k4 += 4) {
        float v0 = vcol[(size_t)(k4 + 0) * DM];
        float v1 = vcol[(size_t)(k4 + 1) * DM];
        float v2 = vcol[(size_t)(k4 + 2) * DM];
        float v3 = vcol[(size_t)(k4 + 3) * DM];
#pragma unroll
        for (int r = 0; r < 16; ++r) {
            float4 p4 = *(const float4*)&prow[(size_t)r * SEQ + k4];
            acc[r] = fmaf(p4.x, v0, acc[r]);
            acc[r] = fmaf(p4.y, v1, acc[r]);
            acc[r] = fmaf(p4.z, v2, acc[r]);
            acc[r] = fmaf(p4.w, v3, acc[r]);
        }
    }
    float* arow = attn + (size_t)(b * SEQ + qt * 64 + wid * 16) * DM + h * 64 + lane;
#pragma unroll
    for (int r = 0; r < 16; ++r) arow[(size_t)r * DM] = acc[r];
}

// ============ w_rel: attn[b,q,h,:] += sum_k P[b,h,q,k] * rv[b,q,k,:] ============
// grid (q=1024, b=2). rv tile LDS-staged (amortized over 12 heads);
// P rows via wave-uniform scalar float4 loads. lane = d.
__global__ __launch_bounds__(256) void wrel_kernel(
    const float* __restrict__ scores, const float* __restrict__ rv,
    float* __restrict__ attn)
{
    const int q = blockIdx.x, b = blockIdx.y;
    __shared__ float RVs[64][65];
    const int tid = threadIdx.x;
    const int d = tid & 63;
    const int hb = __builtin_amdgcn_readfirstlane(tid >> 6);  // heads hb, hb+4, hb+8
    const size_t rbase = ((size_t)(b * SEQ + q)) * SEQ * DK;
    const float* p0 = scores + ((size_t)(b * NH + hb    ) * SEQ + q) * SEQ;
    const float* p1 = scores + ((size_t)(b * NH + hb + 4) * SEQ + q) * SEQ;
    const float* p2 = scores + ((size_t)(b * NH + hb + 8) * SEQ + q) * SEQ;
    float a0 = 0.f, a1 = 0.f, a2 = 0.f;
    for (int kt = 0; kt < 16; ++kt) {
        __syncthreads();
#pragma unroll
        for (int l = 0; l < 4; ++l) {
            int idx = tid + l * 256;
            int kk = idx >> 4, d4 = idx & 15;
            float4 t = *(const float4*)&rv[rbase + (size_t)(kt * 64 + kk) * DK + d4 * 4];
            RVs[kk][d4 * 4 + 0] = t.x;
            RVs[kk][d4 * 4 + 1] = t.y;
            RVs[kk][d4 * 4 + 2] = t.z;
            RVs[kk][d4 * 4 + 3] = t.w;
        }
        __syncthreads();
#pragma unroll
        for (int k4 = 0; k4 < 16; ++k4) {
            float4 P0 = *(const float4*)&p0[kt * 64 + k4 * 4];
            float4 P1 = *(const float4*)&p1[kt * 64 + k4 * 4];
            float4 P2 = *(const float4*)&p2[kt * 64 + k4 * 4];
            float r0 = RVs[k4 * 4 + 0][d];
            float r1 = RVs[k4 * 4 + 1][d];
            float r2 = RVs[k4 * 4 + 2][d];
            float r3 = RVs[k4 * 4 + 3][d];
            a0 = fmaf(P0.x, r0, fmaf(P0.y, r1, fmaf(P0.z, r2, fmaf(P0.w, r3, a0))));
            a1 = fmaf(P1.x, r0, fmaf(P1.y, r1, fmaf(P1.z, r2, fmaf(P1.w, r3, a1))));
            a2 = fmaf(P2.x, r0, fmaf(P2.y, r1, fmaf(P2.z, r2, fmaf(P2.w, r3, a2))));
        }
    }
    float* ap = attn + (size_t)(b * SEQ + q) * DM + d;
    ap[(hb    ) * 64] += a0;
    ap[(hb + 4) * 64] += a1;
    ap[(hb + 8) * 64] += a2;
}

extern "C" void kernel_launch(void* const* d_in, const int* in_sizes, int n_in,
                              void* d_out, int out_size, void* d_ws, size_t ws_size,
                              hipStream_t stream)
{
    const float* queries = (const float*)d_in[0];
    const float* keys    = (const float*)d_in[1];
    const float* values  = (const float*)d_in[2];
    const float* rk      = (const float*)d_in[3];
    const float* rv      = (const float*)d_in[4];
    const float* Wq      = (const float*)d_in[5];
    const float* bq      = (const float*)d_in[6];
    const float* Wk      = (const float*)d_in[7];
    const float* bk      = (const float*)d_in[8];
    const float* Wv      = (const float*)d_in[9];
    const float* bv      = (const float*)d_in[10];
    const float* Wo      = (const float*)d_in[11];
    const float* bo      = (const float*)d_in[12];
    float* out = (float*)d_out;
    float* ws  = (float*)d_ws;

    float* qs    = ws + OFF_QS;
    float* ks    = ws + OFF_KS;
    float* vs    = ws + OFF_VS;
    float* attn  = ws + OFF_ATTN;
    float* sc    = ws + OFF_SC;

    dim3 gblk(256);
    dim3 ggrid(32, 12);
    // projections (q pre-scaled by 1/64: folds q*dk^-0.5 and /sqrt(dk))
    hipLaunchKernelGGL(gemm_bias_kernel, ggrid, gblk, 0, stream, queries, Wq, bq, qs, 1.0f / 64.0f);
    hipLaunchKernelGGL(gemm_bias_kernel, ggrid, gblk, 0, stream, keys,    Wk, bk, ks, 1.0f);
    hipLaunchKernelGGL(gemm_bias_kernel, ggrid, gblk, 0, stream, values,  Wv, bv, vs, 1.0f);
    // logits
    hipLaunchKernelGGL(qk_kernel,   dim3(16, 16, 24), gblk, 0, stream, qs, ks, sc);
    hipLaunchKernelGGL(relk_kernel, dim3(4, 1024, 2), gblk, 0, stream, qs, rk, sc);
    // softmax
    hipLaunchKernelGGL(softmax_kernel, dim3(24576), gblk, 0, stream, sc);
    // PV + relation-V
    hipLaunchKernelGGL(wv_kernel,   dim3(16, 24),   gblk, 0, stream, sc, vs, attn);
    hipLaunchKernelGGL(wrel_kernel, dim3(1024, 2),  gblk, 0, stream, sc, rv, attn);
    // output projection
    hipLaunchKernelGGL(gemm_bias_kernel, ggrid, gblk, 0, stream, attn, Wo, bo, out, 1.0f);
}